// Round 6
// baseline (262.639 us; speedup 1.0000x reference)
//
#include <hip/hip_runtime.h>
#include <math.h>

#define B_  8
#define C_  64
#define H_  128
#define W_  128
#define KK_ 9
#define CO_ 64
#define HW_ (H_*W_)
#define CK_ 576

typedef _Float16 f16x8 __attribute__((ext_vector_type(8)));
typedef _Float16 h2    __attribute__((ext_vector_type(2)));
typedef __attribute__((ext_vector_type(4))) float f32x4;

__device__ inline unsigned pkrtz(float a, float b){
    auto v = __builtin_amdgcn_cvt_pkrtz(a, b);   // __fp16x2 on this toolchain
    union{decltype(v) h; unsigned u;} c; c.h = v; return c.u;
}
__device__ inline h2 u2h(unsigned u){ union{unsigned x; h2 h;} c; c.x = u; return c.h; }
__device__ inline unsigned h2u(h2 v){ union{h2 h; unsigned u;} c; c.h = v; return c.u; }
__device__ inline unsigned short f2h(float f){
    _Float16 h = (_Float16)f;
    union{_Float16 h; unsigned short s;} c; c.h = h; return c.s;
}
// broadcast lo/hi f16 of a dword into both halves (1 v_perm_b32 each)
__device__ inline h2 bcast_lo(unsigned u){ return u2h(__builtin_amdgcn_perm(u, u, 0x01000100)); }
__device__ inline h2 bcast_hi(unsigned u){ return u2h(__builtin_amdgcn_perm(u, u, 0x03020302)); }

// ---- transpose_prep: fused x NCHW->NHWC f16 transpose + weight repack ----
__global__ __launch_bounds__(256) void transpose_prep(
    const float* __restrict__ x, unsigned short* __restrict__ xt,
    const float* __restrict__ w_dcn, const float* __restrict__ w_off,
    unsigned short* __restrict__ w_bf, unsigned short* __restrict__ wA)
{
    __shared__ unsigned tb[64 * 33];          // [pix][ch-pair], stride 33
    if (blockIdx.x >= B_ * 256) {             // weight-repack tail blocks
        int i = (blockIdx.x - B_ * 256) * 256 + threadIdx.x;
        if (i < 64 * CK_) {
            int o = i / CK_, r = i % CK_;
            int tap = r >> 6, c = r & 63;
            w_bf[i] = f2h(w_dcn[o * CK_ + c * 9 + tap]);
        } else {
            int j = i - 64 * CK_;             // 0 .. 32*576-1
            int o = j / CK_, r = j % CK_;
            int tap = r >> 6, c = r & 63;
            float v = (o < 27) ? w_off[o * CK_ + c * 9 + tap] : 0.f;
            wA[j] = f2h(v);
        }
        return;
    }
    int b = blockIdx.x >> 8;
    int pixbase = (blockIdx.x & 255) * 64;
    int t = threadIdx.x;
    #pragma unroll
    for (int i = 0; i < 2; ++i) {
        int idx = i * 256 + t;                // 0..511
        int cp = idx >> 4;                    // ch-pair 0..31
        int p4 = (idx & 15) * 4;              // pix 0..60 step 4
        const float* r0 = x + ((size_t)(b * C_) + 2 * cp    ) * HW_ + pixbase + p4;
        const float* r1 = x + ((size_t)(b * C_) + 2 * cp + 1) * HW_ + pixbase + p4;
        float4 f0 = *(const float4*)r0;
        float4 f1 = *(const float4*)r1;
        tb[(p4 + 0) * 33 + cp] = pkrtz(f0.x, f1.x);
        tb[(p4 + 1) * 33 + cp] = pkrtz(f0.y, f1.y);
        tb[(p4 + 2) * 33 + cp] = pkrtz(f0.z, f1.z);
        tb[(p4 + 3) * 33 + cp] = pkrtz(f0.w, f1.w);
    }
    __syncthreads();
    unsigned* xo = (unsigned*)xt + ((size_t)b * HW_ + pixbase) * 32;
    #pragma unroll
    for (int i = 0; i < 2; ++i) {
        int idx = i * 256 + t;
        int pix = idx >> 3, j = idx & 7;
        uint4 v;
        v.x = tb[pix * 33 + j * 4 + 0];
        v.y = tb[pix * 33 + j * 4 + 1];
        v.z = tb[pix * 33 + j * 4 + 2];
        v.w = tb[pix * 33 + j * 4 + 3];
        *(uint4*)(xo + pix * 32 + j * 4) = v;   // contiguous 1KB per wave-instr
    }
}

// ---- dcn13: STRUCTURAL — wave-owns-pixels partition; barrier-free Phase B.
// Wave w owns pixels w*16..w*16+15 x ALL 64 out-channels. Lane (m,q) samples
// pixel m, channels q*8..q*8+7 -> blended result IS the MFMA B-fragment in
// registers. No sS buffer, no ds_write/ds_read round trip, ZERO Phase-B
// barriers. Cost: A-frags re-read per o-tile from L2-hot w_bf (72KB).
// Per-channel blend math and per-acc MFMA k-order bit-identical to dcn12.
__global__ __launch_bounds__(256, 4) void dcn13(
    const unsigned short* __restrict__ xt,    // f16 NHWC
    const unsigned short* __restrict__ wA,    // offset-conv weights [32][576] f16
    const float* __restrict__ b_off,
    const unsigned short* __restrict__ w_bf,  // dcn weights [64][576] f16
    float* __restrict__ out)
{
    __shared__ __align__(16) float om[27 * 65];   // conv outputs [27][stride 65]
    __shared__ uint2 scr_w[576];              // 4 f16 corner weights (w00,w01,w10,w11)
    __shared__ int   scr_o[576];              // packed corner offsets

    int tile = blockIdx.x;
    int b  = tile >> 8;
    int p0 = (tile & 255) * 64;
    int y  = p0 >> 7;
    int x0 = p0 & 127;                        // 0 or 64
    int t  = threadIdx.x;
    int lane = t & 63, w = t >> 6;
    int m = lane & 15, q = lane >> 4;

    const unsigned short* xbr = xt + (size_t)(b * HW_) * 64;

    // ================= Phase A: offset conv via MFMA (unchanged) ============
    {
        int o0c = (w & 1) * 16;               // conv o-tile
        int pxh = (w >> 1) * 32;              // conv px half (of 64-px tile)

        f32x4 accc[2] = {};
        #pragma unroll
        for (int ky = 0; ky < 3; ++ky) {
            int yy = y + ky - 1;
            if (yy >= 0 && yy < H_) {
                const unsigned short* xr = xbr + (size_t)yy * W_ * 64;
                #pragma unroll
                for (int kx = 0; kx < 3; ++kx) {
                    int s2 = (ky * 3 + kx) * 2;
                    f16x8 A0 = *(const f16x8*)(wA + (o0c + m) * CK_ + s2 * 32 + q * 8);
                    f16x8 A1 = *(const f16x8*)(wA + (o0c + m) * CK_ + (s2 + 1) * 32 + q * 8);
                    #pragma unroll
                    for (int nt = 0; nt < 2; ++nt) {
                        int xbase = x0 + pxh + nt * 16;
                        int px = xbase + m + kx - 1;
                        f16x8 b0, b1;
                        bool ledge = (xbase == 0   && kx == 0);
                        bool redge = (xbase == 112 && kx == 2);
                        if (ledge || redge) {
                            int pc = min(max(px, 0), W_ - 1);
                            const unsigned short* p = xr + pc * 64 + q * 8;
                            b0 = *(const f16x8*)p;
                            b1 = *(const f16x8*)(p + 32);
                            if (px != pc) {
                                b0 = (f16x8){0,0,0,0,0,0,0,0};
                                b1 = (f16x8){0,0,0,0,0,0,0,0};
                            }
                        } else {
                            const unsigned short* p = xr + px * 64 + q * 8;
                            b0 = *(const f16x8*)p;
                            b1 = *(const f16x8*)(p + 32);
                        }
                        accc[nt] = __builtin_amdgcn_mfma_f32_16x16x32_f16(A0, b0, accc[nt], 0, 0, 0);
                        accc[nt] = __builtin_amdgcn_mfma_f32_16x16x32_f16(A1, b1, accc[nt], 0, 0, 0);
                    }
                }
            }
        }
        #pragma unroll
        for (int nt = 0; nt < 2; ++nt) {
            #pragma unroll
            for (int r = 0; r < 4; ++r) {
                int j = o0c + q * 4 + r;
                if (j < 27)
                    om[j * 65 + pxh + nt * 16 + m] = accc[nt][r] + b_off[j];
            }
        }
    }
    __syncthreads();

    // ================= Phase 0: offsets -> 4xf16 weights + packed offsets ===
    for (int i = t; i < 576; i += 256) {
        int k = i >> 6, sp = i & 63;
        float dy = om[(2 * k)     * 65 + sp];
        float dx = om[(2 * k + 1) * 65 + sp];
        float mk = 1.f / (1.f + __expf(-om[(18 + k) * 65 + sp]));
        float py = dy + (float)(y - 1 + k / 3);
        float px = dx + (float)(x0 + sp - 1 + k % 3);
        float fy = floorf(py), fx = floorf(px);
        int iy = (int)fy, ix = (int)fx;
        float ay = py - fy, ax = px - fx;
        float wy0 = (iy >= 0  && iy < H_)     ? (1.f - ay) : 0.f;
        float wy1 = (iy >= -1 && iy < H_ - 1) ? ay         : 0.f;
        float wx0 = (ix >= 0  && ix < W_)     ? (1.f - ax) : 0.f;
        float wx1 = (ix >= -1 && ix < W_ - 1) ? ax         : 0.f;
        int iy0 = min(max(iy, 0), H_ - 1);
        int iy1 = min(max(iy + 1, 0), H_ - 1);
        int ix0 = min(max(ix, 0), W_ - 1);
        int ix1 = min(max(ix + 1, 0), W_ - 1);
        float w00 = wy0*wx0*mk, w01 = wy0*wx1*mk, w10 = wy1*wx0*mk, w11 = wy1*wx1*mk;
        uint2 wv;
        wv.x = pkrtz(w00, w01);               // lo=w00 hi=w01
        wv.y = pkrtz(w10, w11);               // lo=w10 hi=w11
        scr_w[i] = wv;
        int off00 = (iy0 * W_ + ix0) * 128;   // bytes (64ch * 2B f16)
        scr_o[i] = off00 | ((ix1 != ix0) << 22) | ((iy1 != iy0) << 23);
    }
    __syncthreads();        // scr ready — LAST barrier in the kernel

    // ================= Phase B: barrier-free in-register sampling + GEMM ====
    // Lane (m,q): pixel px = w*16+m, channels q*8..q*8+7 (frag0) and
    // 32+q*8..39 (frag1). Blended output IS the B-fragment.
    int px = w * 16 + m;                      // block-local pixel
    const unsigned char* xb = (const unsigned char*)xbr;
    f32x4 acc[4] = {};                        // o-tiles jo=0..3

    #pragma unroll
    for (int tap = 0; tap < 9; ++tap) {
        uint2 wv = scr_w[tap * 64 + px];      // 16 addrs x 4-way broadcast: conflict-free
        int   oo = scr_o[tap * 64 + px];
        const unsigned char* a0 = xb + (oo & 0x3FFFFF) + q * 16;
        int dxb = (oo >> 15) & 128;
        int dyb = (oo >> 9)  & 16384;
        uint4 cA0 = *(const uint4*)(a0);
        uint4 cA1 = *(const uint4*)(a0 + dxb);
        uint4 cA2 = *(const uint4*)(a0 + dyb);
        uint4 cA3 = *(const uint4*)(a0 + dyb + dxb);
        uint4 cB0 = *(const uint4*)(a0 + 64);
        uint4 cB1 = *(const uint4*)(a0 + 64 + dxb);
        uint4 cB2 = *(const uint4*)(a0 + 64 + dyb);
        uint4 cB3 = *(const uint4*)(a0 + 64 + dyb + dxb);

        h2 w00 = bcast_lo(wv.x), w01 = bcast_hi(wv.x);
        h2 w10 = bcast_lo(wv.y), w11 = bcast_hi(wv.y);

        union { uint4 u; f16x8 h; } f0, f1;
        f0.u.x = h2u(w00*u2h(cA0.x) + w01*u2h(cA1.x) + w10*u2h(cA2.x) + w11*u2h(cA3.x));
        f0.u.y = h2u(w00*u2h(cA0.y) + w01*u2h(cA1.y) + w10*u2h(cA2.y) + w11*u2h(cA3.y));
        f0.u.z = h2u(w00*u2h(cA0.z) + w01*u2h(cA1.z) + w10*u2h(cA2.z) + w11*u2h(cA3.z));
        f0.u.w = h2u(w00*u2h(cA0.w) + w01*u2h(cA1.w) + w10*u2h(cA2.w) + w11*u2h(cA3.w));
        f1.u.x = h2u(w00*u2h(cB0.x) + w01*u2h(cB1.x) + w10*u2h(cB2.x) + w11*u2h(cB3.x));
        f1.u.y = h2u(w00*u2h(cB0.y) + w01*u2h(cB1.y) + w10*u2h(cB2.y) + w11*u2h(cB3.y));
        f1.u.z = h2u(w00*u2h(cB0.z) + w01*u2h(cB1.z) + w10*u2h(cB2.z) + w11*u2h(cB3.z));
        f1.u.w = h2u(w00*u2h(cB0.w) + w01*u2h(cB1.w) + w10*u2h(cB2.w) + w11*u2h(cB3.w));

        const unsigned short* wb = w_bf + tap * 64 + q * 8;
        #pragma unroll
        for (int jo = 0; jo < 4; ++jo) {
            f16x8 A0 = *(const f16x8*)(wb + (jo * 16 + m) * CK_);
            f16x8 A1 = *(const f16x8*)(wb + (jo * 16 + m) * CK_ + 32);
            acc[jo] = __builtin_amdgcn_mfma_f32_16x16x32_f16(A0, f0.h, acc[jo], 0, 0, 0);
            acc[jo] = __builtin_amdgcn_mfma_f32_16x16x32_f16(A1, f1.h, acc[jo], 0, 0, 0);
        }
    }

    // Epilogue: col(px)=m, row(o)=q*4+reg; wave's pixels p0+w*16..+15
    #pragma unroll
    for (int jo = 0; jo < 4; ++jo) {
        #pragma unroll
        for (int r = 0; r < 4; ++r) {
            int o = jo * 16 + q * 4 + r;
            out[((size_t)(b * CO_ + o)) * HW_ + p0 + w * 16 + m] = acc[jo][r];
        }
    }
}

extern "C" void kernel_launch(void* const* d_in, const int* in_sizes, int n_in,
                              void* d_out, int out_size, void* d_ws, size_t ws_size,
                              hipStream_t stream)
{
    const float* x     = (const float*)d_in[0];
    const float* w_off = (const float*)d_in[1];
    const float* b_off = (const float*)d_in[2];
    const float* w_dcn = (const float*)d_in[3];
    float* out = (float*)d_out;

    unsigned short* xt   = (unsigned short*)d_ws;                // B*HW*64 f16 (8.4 MB)
    unsigned short* w_bf = xt + (size_t)B_ * HW_ * 64;
    unsigned short* wA   = w_bf + 64 * CK_;

    transpose_prep<<<B_ * 256 + 216, 256, 0, stream>>>(x, xt, w_dcn, w_off, w_bf, wA);
    dcn13<<<B_ * 256, 256, 0, stream>>>(xt, wA, b_off, w_bf, out);
}

// Round 8
// 173.216 us; speedup vs baseline: 1.5163x; 1.5163x over previous
//
#include <hip/hip_runtime.h>
#include <math.h>

#define B_  8
#define C_  64
#define H_  128
#define W_  128
#define KK_ 9
#define CO_ 64
#define HW_ (H_*W_)
#define CK_ 576

typedef _Float16 f16x8 __attribute__((ext_vector_type(8)));
typedef _Float16 h2    __attribute__((ext_vector_type(2)));
typedef __attribute__((ext_vector_type(4))) float f32x4;
typedef unsigned int u32x4 __attribute__((ext_vector_type(4)));

__device__ inline unsigned pkrtz(float a, float b){
    auto v = __builtin_amdgcn_cvt_pkrtz(a, b);   // __fp16x2 on this toolchain
    union{decltype(v) h; unsigned u;} c; c.h = v; return c.u;
}
__device__ inline h2 u2h(unsigned u){ union{unsigned x; h2 h;} c; c.x = u; return c.h; }
__device__ inline unsigned h2u(h2 v){ union{h2 h; unsigned u;} c; c.h = v; return c.u; }
__device__ inline unsigned short f2h(float f){
    _Float16 h = (_Float16)f;
    union{_Float16 h; unsigned short s;} c; c.h = h; return c.s;
}
// broadcast lo/hi f16 of a dword into both halves (1 v_perm_b32 each)
__device__ inline h2 bcast_lo(unsigned u){ return u2h(__builtin_amdgcn_perm(u, u, 0x01000100)); }
__device__ inline h2 bcast_hi(unsigned u){ return u2h(__builtin_amdgcn_perm(u, u, 0x03020302)); }

// ---- transpose_prep: fused x NCHW->NHWC f16 transpose + weight repack ----
__global__ __launch_bounds__(256) void transpose_prep(
    const float* __restrict__ x, unsigned short* __restrict__ xt,
    const float* __restrict__ w_dcn, const float* __restrict__ w_off,
    unsigned short* __restrict__ w_bf, unsigned short* __restrict__ wA)
{
    __shared__ unsigned tb[64 * 33];          // [pix][ch-pair], stride 33
    if (blockIdx.x >= B_ * 256) {             // weight-repack tail blocks
        int i = (blockIdx.x - B_ * 256) * 256 + threadIdx.x;
        if (i < 64 * CK_) {
            int o = i / CK_, r = i % CK_;
            int tap = r >> 6, c = r & 63;
            w_bf[i] = f2h(w_dcn[o * CK_ + c * 9 + tap]);
        } else {
            int j = i - 64 * CK_;             // 0 .. 32*576-1
            int o = j / CK_, r = j % CK_;
            int tap = r >> 6, c = r & 63;
            float v = (o < 27) ? w_off[o * CK_ + c * 9 + tap] : 0.f;
            wA[j] = f2h(v);
        }
        return;
    }
    int b = blockIdx.x >> 8;
    int pixbase = (blockIdx.x & 255) * 64;
    int t = threadIdx.x;
    #pragma unroll
    for (int i = 0; i < 2; ++i) {
        int idx = i * 256 + t;                // 0..511
        int cp = idx >> 4;                    // ch-pair 0..31
        int p4 = (idx & 15) * 4;              // pix 0..60 step 4
        const float* r0 = x + ((size_t)(b * C_) + 2 * cp    ) * HW_ + pixbase + p4;
        const float* r1 = x + ((size_t)(b * C_) + 2 * cp + 1) * HW_ + pixbase + p4;
        float4 f0 = *(const float4*)r0;
        float4 f1 = *(const float4*)r1;
        tb[(p4 + 0) * 33 + cp] = pkrtz(f0.x, f1.x);
        tb[(p4 + 1) * 33 + cp] = pkrtz(f0.y, f1.y);
        tb[(p4 + 2) * 33 + cp] = pkrtz(f0.z, f1.z);
        tb[(p4 + 3) * 33 + cp] = pkrtz(f0.w, f1.w);
    }
    __syncthreads();
    unsigned* xo = (unsigned*)xt + ((size_t)b * HW_ + pixbase) * 32;
    #pragma unroll
    for (int i = 0; i < 2; ++i) {
        int idx = i * 256 + t;
        int pix = idx >> 3, j = idx & 7;
        uint4 v;
        v.x = tb[pix * 33 + j * 4 + 0];
        v.y = tb[pix * 33 + j * 4 + 1];
        v.z = tb[pix * 33 + j * 4 + 2];
        v.w = tb[pix * 33 + j * 4 + 3];
        *(uint4*)(xo + pix * 32 + j * 4) = v;   // contiguous 1KB per wave-instr
    }
}

// ---- dcn14b: round-6 dcn14 resubmission (infra failure, no data), with the
// 4-output mega-asm split into four single-load asm statements (regalloc
// hardening; identical vmcnt arithmetic). Diagnosis unchanged: C-level
// prefetch collapsed by compiler (VGPR pinned 44-48 -> zero lookahead);
// enforce depth-1 double-buffered gather pipeline via opaque asm loads +
// counted s_waitcnt vmcnt(4) + sched_barrier(0) (guide §5/T4/rule#18).
#define SSTR4 400     // sS row stride bytes, 16B aligned
__global__ __launch_bounds__(256, 4) void dcn14b(
    const unsigned short* __restrict__ xt,    // f16 NHWC
    const unsigned short* __restrict__ wA,    // offset-conv weights [32][576] f16
    const float* __restrict__ b_off,
    const unsigned short* __restrict__ w_bf,  // dcn weights [64][576] f16
    float* __restrict__ out)
{
    __shared__ __align__(16) unsigned char sS[64 * SSTR4];  // 25600 B (aliases om)
    __shared__ uint2 scr_w[576];              // 4 f16 corner weights (w00,w01,w10,w11)
    __shared__ int   scr_o[576];              // packed corner offsets
    float* om = (float*)sS;                   // [27][stride 65] conv outputs

    int tile = blockIdx.x;
    int b  = tile >> 8;
    int p0 = (tile & 255) * 64;
    int y  = p0 >> 7;
    int x0 = p0 & 127;                        // 0 or 64
    int t  = threadIdx.x;
    int lane = t & 63, w = t >> 6;
    int m = lane & 15, q = lane >> 4;

    const unsigned short* xbr = xt + (size_t)(b * HW_) * 64;

    // ================= Phase A: offset conv via MFMA (unchanged) ============
    {
        int o0c = (w & 1) * 16;               // conv o-tile
        int pxh = (w >> 1) * 32;              // conv px half (of 64-px tile)

        f32x4 accc[2] = {};
        #pragma unroll
        for (int ky = 0; ky < 3; ++ky) {
            int yy = y + ky - 1;
            if (yy >= 0 && yy < H_) {
                const unsigned short* xr = xbr + (size_t)yy * W_ * 64;
                #pragma unroll
                for (int kx = 0; kx < 3; ++kx) {
                    int s2 = (ky * 3 + kx) * 2;
                    f16x8 A0 = *(const f16x8*)(wA + (o0c + m) * CK_ + s2 * 32 + q * 8);
                    f16x8 A1 = *(const f16x8*)(wA + (o0c + m) * CK_ + (s2 + 1) * 32 + q * 8);
                    #pragma unroll
                    for (int nt = 0; nt < 2; ++nt) {
                        int xbase = x0 + pxh + nt * 16;
                        int px = xbase + m + kx - 1;
                        f16x8 b0, b1;
                        bool ledge = (xbase == 0   && kx == 0);
                        bool redge = (xbase == 112 && kx == 2);
                        if (ledge || redge) {
                            int pc = min(max(px, 0), W_ - 1);
                            const unsigned short* p = xr + pc * 64 + q * 8;
                            b0 = *(const f16x8*)p;
                            b1 = *(const f16x8*)(p + 32);
                            if (px != pc) {
                                b0 = (f16x8){0,0,0,0,0,0,0,0};
                                b1 = (f16x8){0,0,0,0,0,0,0,0};
                            }
                        } else {
                            const unsigned short* p = xr + px * 64 + q * 8;
                            b0 = *(const f16x8*)p;
                            b1 = *(const f16x8*)(p + 32);
                        }
                        accc[nt] = __builtin_amdgcn_mfma_f32_16x16x32_f16(A0, b0, accc[nt], 0, 0, 0);
                        accc[nt] = __builtin_amdgcn_mfma_f32_16x16x32_f16(A1, b1, accc[nt], 0, 0, 0);
                    }
                }
            }
        }
        #pragma unroll
        for (int nt = 0; nt < 2; ++nt) {
            #pragma unroll
            for (int r = 0; r < 4; ++r) {
                int j = o0c + q * 4 + r;
                if (j < 27)
                    om[j * 65 + pxh + nt * 16 + m] = accc[nt][r] + b_off[j];
            }
        }
    }
    __syncthreads();

    // ================= Phase 0: offsets -> 4xf16 weights + packed offsets ===
    for (int i = t; i < 576; i += 256) {
        int k = i >> 6, sp = i & 63;
        float dy = om[(2 * k)     * 65 + sp];
        float dx = om[(2 * k + 1) * 65 + sp];
        float mk = 1.f / (1.f + __expf(-om[(18 + k) * 65 + sp]));
        float py = dy + (float)(y - 1 + k / 3);
        float px = dx + (float)(x0 + sp - 1 + k % 3);
        float fy = floorf(py), fx = floorf(px);
        int iy = (int)fy, ix = (int)fx;
        float ay = py - fy, ax = px - fx;
        float wy0 = (iy >= 0  && iy < H_)     ? (1.f - ay) : 0.f;
        float wy1 = (iy >= -1 && iy < H_ - 1) ? ay         : 0.f;
        float wx0 = (ix >= 0  && ix < W_)     ? (1.f - ax) : 0.f;
        float wx1 = (ix >= -1 && ix < W_ - 1) ? ax         : 0.f;
        int iy0 = min(max(iy, 0), H_ - 1);
        int iy1 = min(max(iy + 1, 0), H_ - 1);
        int ix0 = min(max(ix, 0), W_ - 1);
        int ix1 = min(max(ix + 1, 0), W_ - 1);
        float w00 = wy0*wx0*mk, w01 = wy0*wx1*mk, w10 = wy1*wx0*mk, w11 = wy1*wx1*mk;
        uint2 wv;
        wv.x = pkrtz(w00, w01);               // lo=w00 hi=w01
        wv.y = pkrtz(w10, w11);               // lo=w10 hi=w11
        scr_w[i] = wv;
        int off00 = (iy0 * W_ + ix0) * 128;   // bytes (64ch * 2B f16)
        scr_o[i] = off00 | ((ix1 != ix0) << 22) | ((iy1 != iy0) << 23);
    }

    int o0 = w * 16;
    __syncthreads();        // scr ready; om region (sS) now free

    // ================= Phase B: asm-pipelined sampling + GEMM ===============
    int cq = lane & 7;      // channel oct (8 ch = 16B)
    int g  = lane >> 3;     // pixel-tap sub-index (8 per wave per it)
    const unsigned char* xb = (const unsigned char*)xbr;
    f32x4 acc[4] = {};
    int piB = w * 8 + g;    // global pixel-tap P = piB + k*32, k = 0..17

// Opaque gather issue: 4 separate single-load asm statements (regalloc-
// friendly); compiler cannot sink them. Each GISSUE = +4 vmcnt.
#define GISSUE(N0,N1,N2,N3, PK) do {                                       \
        const unsigned char* _a0 = xb + ((PK) & 0x3FFFFF) + cq * 16;       \
        int _dx = ((PK) >> 15) & 128;                                      \
        int _dy = ((PK) >> 9)  & 16384;                                    \
        const unsigned char* _a1 = _a0 + _dx;                              \
        const unsigned char* _a2 = _a0 + _dy;                              \
        const unsigned char* _a3 = _a2 + _dx;                              \
        asm volatile("global_load_dwordx4 %0, %1, off" : "=v"(N0) : "v"(_a0)); \
        asm volatile("global_load_dwordx4 %0, %1, off" : "=v"(N1) : "v"(_a1)); \
        asm volatile("global_load_dwordx4 %0, %1, off" : "=v"(N2) : "v"(_a2)); \
        asm volatile("global_load_dwordx4 %0, %1, off" : "=v"(N3) : "v"(_a3)); \
    } while (0)

// Blend set (S0..S3 = corners 00,01,10,11) with weights WQ; store to sS.
#define BLEND_STORE(S0,S1,S2,S3, WQ, K, IT6) do {                          \
        h2 w00 = bcast_lo((WQ).x), w01 = bcast_hi((WQ).x);                 \
        h2 w10 = bcast_lo((WQ).y), w11 = bcast_hi((WQ).y);                 \
        u32x4 o4; h2 r;                                                    \
        r = w00*u2h(S0.x) + w01*u2h(S1.x) + w10*u2h(S2.x) + w11*u2h(S3.x); o4.x = h2u(r); \
        r = w00*u2h(S0.y) + w01*u2h(S1.y) + w10*u2h(S2.y) + w11*u2h(S3.y); o4.y = h2u(r); \
        r = w00*u2h(S0.z) + w01*u2h(S1.z) + w10*u2h(S2.z) + w11*u2h(S3.z); o4.z = h2u(r); \
        r = w00*u2h(S0.w) + w01*u2h(S1.w) + w10*u2h(S2.w) + w11*u2h(S3.w); o4.w = h2u(r); \
        int sp  = (piB + ((K) & 1) * 32) & 63;                             \
        int ktl = (IT6) >> 1;                                              \
        *(u32x4*)&sS[sp * SSTR4 + ktl * 128 + cq * 16] = o4;               \
    } while (0)

    // two corner register sets, alternating by k parity (k even: A, odd: B)
    u32x4 A0_, A1_, A2_, A3_, B0_, B1_, B2_, B3_;
    uint2 wA_, wB_; int pB_;
    {
        wA_ = scr_w[piB];      int oo = scr_o[piB];
        wB_ = scr_w[piB + 32]; pB_ = scr_o[piB + 32];
        GISSUE(A0_, A1_, A2_, A3_, oo);       // corners k=0 -> set A
    }

    #pragma unroll
    for (int chunk = 0; chunk < 3; ++chunk) {
        #pragma unroll
        for (int it6 = 0; it6 < 6; ++it6) {
            const int k = chunk * 6 + it6;
            // scr prefetch 2 ahead (LDS; compiler-managed lgkmcnt)
            uint2 wC_ = {}; int pC_ = 0;
            if (k + 2 < 18) {
                int P = piB + (k + 2) * 32;
                wC_ = scr_w[P]; pC_ = scr_o[P];
            }
            // issue k+1 gathers into the alternate set; counted wait for k
            if (k + 1 < 18) {
                if (k & 1) GISSUE(A0_, A1_, A2_, A3_, pB_);
                else       GISSUE(B0_, B1_, B2_, B3_, pB_);
                asm volatile("s_waitcnt vmcnt(4)");
            } else {
                asm volatile("s_waitcnt vmcnt(0)");
            }
            __builtin_amdgcn_sched_barrier(0);   // rule #18: pin blend below wait
            if (k & 1) BLEND_STORE(B0_, B1_, B2_, B3_, wA_, k, it6);
            else       BLEND_STORE(A0_, A1_, A2_, A3_, wA_, k, it6);
            // rotate scr pipeline
            wA_ = wB_; wB_ = wC_; pB_ = pC_;
        }
        // dcn A-frags for this chunk (compiler-tracked loads; in-order vmcnt
        // completion keeps all counted waits conservative-correct)
        f16x8 Af[6];
        #pragma unroll
        for (int s = 0; s < 6; ++s)
            Af[s] = *(const f16x8*)(w_bf + (o0 + m) * CK_ + (chunk * 6 + s) * 32 + q * 8);
        __syncthreads();        // sS chunk ready

        #pragma unroll
        for (int s = 0; s < 6; ++s) {
            #pragma unroll
            for (int nt = 0; nt < 4; ++nt) {
                f16x8 bb = *(const f16x8*)&sS[(nt * 16 + m) * SSTR4 + s * 64 + q * 16];
                acc[nt] = __builtin_amdgcn_mfma_f32_16x16x32_f16(Af[s], bb, acc[nt], 0, 0, 0);
            }
        }
        __syncthreads();        // sS consumed; next producer may overwrite
    }

    // Epilogue: col(px)=m, row(o)=q*4+reg
    #pragma unroll
    for (int nt = 0; nt < 4; ++nt) {
        #pragma unroll
        for (int r = 0; r < 4; ++r) {
            int o = o0 + q * 4 + r;
            out[((size_t)(b * CO_ + o)) * HW_ + p0 + nt * 16 + m] = acc[nt][r];
        }
    }
#undef GISSUE
#undef BLEND_STORE
}

extern "C" void kernel_launch(void* const* d_in, const int* in_sizes, int n_in,
                              void* d_out, int out_size, void* d_ws, size_t ws_size,
                              hipStream_t stream)
{
    const float* x     = (const float*)d_in[0];
    const float* w_off = (const float*)d_in[1];
    const float* b_off = (const float*)d_in[2];
    const float* w_dcn = (const float*)d_in[3];
    float* out = (float*)d_out;

    unsigned short* xt   = (unsigned short*)d_ws;                // B*HW*64 f16 (8.4 MB)
    unsigned short* w_bf = xt + (size_t)B_ * HW_ * 64;
    unsigned short* wA   = w_bf + 64 * CK_;

    transpose_prep<<<B_ * 256 + 216, 256, 0, stream>>>(x, xt, w_dcn, w_off, w_bf, wA);
    dcn14b<<<B_ * 256, 256, 0, stream>>>(xt, wA, b_off, w_bf, out);
}